// Round 10
// baseline (243.919 us; speedup 1.0000x reference)
//
#include <hip/hip_runtime.h>

#define N_NODES 20000
#define D_FEAT 256
#define N_SUPPORT 3
#define N_EDGES 320000
#define OUT_DIM 256
#define TOTAL_E (N_SUPPORT * N_EDGES)
#define CAP 64                      // per-(s,dst) bucket; mean 16, P(>64) ~ 1e-9
#define KDIM (N_SUPPORT * D_FEAT)   // 768
#define HPAD (KDIM + 8)             // 776 shorts; rows 16B-aligned
#define TILE 16
#define QCOLS 64                    // columns per quarter-table pass
#define XQ_ELEMS (N_NODES * QCOLS)  // 1,280,000 shorts = 2.56 MB per quarter

typedef __attribute__((ext_vector_type(8))) short short8;
typedef __attribute__((ext_vector_type(4))) float f32x4;

__device__ inline unsigned short f2bf(float f) {
    unsigned int u = __float_as_uint(f);
    u += 0x7fff + ((u >> 16) & 1);  // round-to-nearest-even
    return (unsigned short)(u >> 16);
}

// ---------------- prep: convert_x (quarter layout) | convert_w | fill_edges ----------------
#define NB_X 5000                   // 20000*64 float4s / 256 threads
#define NB_W (N_SUPPORT * D_FEAT)   // 768
#define NB_F (TOTAL_E / 256)        // 3750

__global__ void __launch_bounds__(256) prep(const float* __restrict__ x, const float* __restrict__ W,
        const int* __restrict__ src, const int* __restrict__ dst, const float* __restrict__ w,
        unsigned short* __restrict__ xq, unsigned short* __restrict__ wt,
        int* __restrict__ cursor, unsigned int* __restrict__ epack) {
    const int bid = blockIdx.x;
    const int tid = threadIdx.x;
    if (bid < NB_X) {
        const int i = bid * 256 + tid;     // float4 id over [20000 x 64)
        const int row = i >> 6;
        const int j = i & 63;
        const int q = j >> 4, c4 = j & 15;
        float4 v = ((const float4*)x)[i];
        ushort4 o;
        o.x = f2bf(v.x); o.y = f2bf(v.y); o.z = f2bf(v.z); o.w = f2bf(v.w);
        ((ushort4*)(xq + (size_t)q * XQ_ELEMS))[row * 16 + c4] = o;
    } else if (bid < NB_X + NB_W) {
        const int row = bid - NB_X;        // s*256 + k
        const int s = row >> 8, k = row & 255;
        wt[((size_t)s * OUT_DIM + tid) * D_FEAT + k] = f2bf(W[(size_t)row * OUT_DIM + tid]);
    } else {
        const int i = (bid - NB_X - NB_W) * 256 + tid;
        const int s = i / N_EDGES;
        const int b = s * N_NODES + dst[i];
        const int pos = atomicAdd(&cursor[b], 1);
        if (pos < CAP)
            epack[(size_t)b * CAP + pos] = (unsigned int)src[i] | (((unsigned int)f2bf(w[i])) << 16);
    }
}

// ---------------- fused: 4-pass column-split gather -> h (LDS) -> h @ W via MFMA ----------------
// 16-node dst tile, 512 threads (8 waves). Phase 1: each 32-lane half owns one
// node; 4 passes over 64-col quarter tables (2.56 MB each, L2-resident);
// per edge-pass each lane loads 4 B (2 cols), ILP-4 via uint4 record loads.
// Phase 2: wave = 2 n-tiles x 24 k-steps (unchanged, round-2-verified mapping).
__global__ void __launch_bounds__(512) fused_gather_gemm(
        const unsigned short* __restrict__ xq, const unsigned short* __restrict__ wt,
        const int* __restrict__ cursor, const unsigned int* __restrict__ epack,
        float* __restrict__ out) {
    __shared__ unsigned short h[TILE][HPAD];   // 24,832 B
    const int n0 = blockIdx.x * TILE;
    const int wid = threadIdx.x >> 6;
    const int lane = threadIdx.x & 63;
    const int half = lane >> 5;
    const int l32 = lane & 31;

    // ---- phase 1 ----
    const int lr = wid * 2 + half;
    const int node = n0 + lr;
    int cnt0 = cursor[node];               if (cnt0 > CAP) cnt0 = CAP;
    int cnt1 = cursor[N_NODES + node];     if (cnt1 > CAP) cnt1 = CAP;
    int cnt2 = cursor[2 * N_NODES + node]; if (cnt2 > CAP) cnt2 = CAP;
    const unsigned int* ep0 = epack + (size_t)node * CAP;
    const unsigned int* ep1 = epack + (size_t)(N_NODES + node) * CAP;
    const unsigned int* ep2 = epack + (size_t)(2 * N_NODES + node) * CAP;

#pragma unroll
    for (int p = 0; p < 4; ++p) {
        const unsigned short* xt = xq + (size_t)p * XQ_ELEMS + l32 * 2;
#pragma unroll
        for (int s = 0; s < N_SUPPORT; ++s) {
            const unsigned int* eps = (s == 0) ? ep0 : (s == 1) ? ep1 : ep2;
            const int c = (s == 0) ? cnt0 : (s == 1) ? cnt1 : cnt2;

            float alo = 0.f, ahi = 0.f;
            int it = 0;
            for (; it + 3 < c; it += 4) {      // 4 independent 4B table loads in flight
                const uint4 pk = *(const uint4*)(eps + it);
                const unsigned int u0 = *(const unsigned int*)(xt + (size_t)(pk.x & 0xFFFFu) * QCOLS);
                const unsigned int u1 = *(const unsigned int*)(xt + (size_t)(pk.y & 0xFFFFu) * QCOLS);
                const unsigned int u2 = *(const unsigned int*)(xt + (size_t)(pk.z & 0xFFFFu) * QCOLS);
                const unsigned int u3 = *(const unsigned int*)(xt + (size_t)(pk.w & 0xFFFFu) * QCOLS);
                const float w0 = __uint_as_float(pk.x & 0xFFFF0000u);
                const float w1 = __uint_as_float(pk.y & 0xFFFF0000u);
                const float w2 = __uint_as_float(pk.z & 0xFFFF0000u);
                const float w3 = __uint_as_float(pk.w & 0xFFFF0000u);
                alo += w0 * __uint_as_float(u0 << 16) + w1 * __uint_as_float(u1 << 16);
                alo += w2 * __uint_as_float(u2 << 16) + w3 * __uint_as_float(u3 << 16);
                ahi += w0 * __uint_as_float(u0 & 0xFFFF0000u) + w1 * __uint_as_float(u1 & 0xFFFF0000u);
                ahi += w2 * __uint_as_float(u2 & 0xFFFF0000u) + w3 * __uint_as_float(u3 & 0xFFFF0000u);
            }
            for (; it < c; ++it) {             // <=3 cleanup iterations
                const unsigned int pe = eps[it];
                const unsigned int u = *(const unsigned int*)(xt + (size_t)(pe & 0xFFFFu) * QCOLS);
                const float wv = __uint_as_float(pe & 0xFFFF0000u);
                alo += wv * __uint_as_float(u << 16);
                ahi += wv * __uint_as_float(u & 0xFFFF0000u);
            }

            // write the 2-col slice of h: cols s*256 + p*64 + l32*2 (+1)
            const unsigned int packed = (unsigned int)f2bf(alo) | (((unsigned int)f2bf(ahi)) << 16);
            *(unsigned int*)&h[lr][s * D_FEAT + p * QCOLS + l32 * 2] = packed;
        }
    }
    __syncthreads();

    // ---- phase 2: out_tile[16][256] = h @ W; wave -> 2 n-tiles ----
    const int cit = lane & 15;
    const int kgrp = (lane >> 4) * 8;

    f32x4 acc[2];
#pragma unroll
    for (int j = 0; j < 2; ++j) acc[j] = (f32x4){0.f, 0.f, 0.f, 0.f};

#pragma unroll
    for (int kk = 0; kk < KDIM / 32; ++kk) {   // 24 k-steps
        const int k0 = kk * 32;
        short8 av = *(const short8*)&h[cit][k0 + kgrp];
        const int s = k0 >> 8;
        const int kp = (k0 & 255) + kgrp;
        const short* bbase = (const short*)wt + (size_t)s * D_FEAT * OUT_DIM
                           + (size_t)cit * D_FEAT + kp;
#pragma unroll
        for (int j = 0; j < 2; ++j) {
            const int nt = wid * 2 + j;
            short8 bv = *(const short8*)(bbase + (size_t)nt * 16 * D_FEAT);
            acc[j] = __builtin_amdgcn_mfma_f32_16x16x32_bf16(av, bv, acc[j], 0, 0, 0);
        }
    }

    // C-write (round-2-verified mapping): row = rbase+r, col = nt*16 + cit
    const int rbase = (lane >> 4) * 4;
#pragma unroll
    for (int j = 0; j < 2; ++j) {
        const int col = (wid * 2 + j) * 16 + cit;
#pragma unroll
        for (int r = 0; r < 4; ++r) {
            out[(size_t)(n0 + rbase + r) * OUT_DIM + col] = acc[j][r];
        }
    }
}

extern "C" void kernel_launch(void* const* d_in, const int* in_sizes, int n_in,
                              void* d_out, int out_size, void* d_ws, size_t ws_size,
                              hipStream_t stream) {
    const float* x        = (const float*)d_in[0];
    const int*   edge_src = (const int*)d_in[1];
    const int*   edge_dst = (const int*)d_in[2];
    const float* edge_w   = (const float*)d_in[3];
    const float* W        = (const float*)d_in[4];
    float* out = (float*)d_out;

    char* ws = (char*)d_ws;
    unsigned short* xq     = (unsigned short*)(ws);              // 4 x 2,560,000 = 10,240,000 B
    unsigned short* wt     = (unsigned short*)(ws + 10240000);   //    393,216 B
    int*            cursor = (int*)(ws + 10633216);              //    240,000 B
    unsigned int*   epack  = (unsigned int*)(ws + 10873216);     // 15,360,000 B
    // total: 26,233,216 B

    hipMemsetAsync(cursor, 0, 240000, stream);

    prep<<<NB_X + NB_W + NB_F, 256, 0, stream>>>(x, W, edge_src, edge_dst, edge_w,
                                                 xq, wt, cursor, epack);

    fused_gather_gemm<<<N_NODES / TILE, 512, 0, stream>>>(xq, wt, cursor, epack, out);
}

// Round 11
// 206.393 us; speedup vs baseline: 1.1818x; 1.1818x over previous
//
#include <hip/hip_runtime.h>

#define N_NODES 20000
#define D_FEAT 256
#define N_SUPPORT 3
#define N_EDGES 320000
#define OUT_DIM 256
#define TOTAL_E (N_SUPPORT * N_EDGES)
#define KDIM (N_SUPPORT * D_FEAT)   // 768
#define HPAD (KDIM + 8)             // 776 shorts; rows 16B-aligned
#define TILE 16
#define NCHUNK 4                    // src-row chunks of 5000 rows (2.56 MB of xb each)
#define CHDIV 5000
#define CAP_SUB 24                  // per-(s,dst,chunk); Poisson(4), P(>24) ~ 1e-13

typedef __attribute__((ext_vector_type(8))) short short8;
typedef __attribute__((ext_vector_type(8))) unsigned short ushort8;
typedef __attribute__((ext_vector_type(4))) float f32x4;

__device__ inline unsigned short f2bf(float f) {
    unsigned int u = __float_as_uint(f);
    u += 0x7fff + ((u >> 16) & 1);  // round-to-nearest-even
    return (unsigned short)(u >> 16);
}
__device__ inline float bf2f(unsigned short u) {
    return __uint_as_float(((unsigned int)u) << 16);
}

// ---------------- prep: convert_x | convert_w | fill_edges (sub-bucketed) ----------------
#define NB_X 5000                   // 20000*256/4 float4 / 256 threads
#define NB_W (N_SUPPORT * D_FEAT)   // 768
#define NB_F (TOTAL_E / 256)        // 3750

__global__ void __launch_bounds__(256) prep(const float* __restrict__ x, const float* __restrict__ W,
        const int* __restrict__ src, const int* __restrict__ dst, const float* __restrict__ w,
        unsigned short* __restrict__ xb, unsigned short* __restrict__ wt,
        int* __restrict__ cursor, unsigned int* __restrict__ epack) {
    const int bid = blockIdx.x;
    const int tid = threadIdx.x;
    if (bid < NB_X) {
        const int i = bid * 256 + tid;
        float4 v = ((const float4*)x)[i];
        ushort4 o;
        o.x = f2bf(v.x); o.y = f2bf(v.y); o.z = f2bf(v.z); o.w = f2bf(v.w);
        ((ushort4*)xb)[i] = o;
    } else if (bid < NB_X + NB_W) {
        const int row = bid - NB_X;        // s*256 + k
        const int s = row >> 8, k = row & 255;
        wt[((size_t)s * OUT_DIM + tid) * D_FEAT + k] = f2bf(W[(size_t)row * OUT_DIM + tid]);
    } else {
        const int i = (bid - NB_X - NB_W) * 256 + tid;
        const int s = i / N_EDGES;
        const int sv = src[i];
        const int b = (s * N_NODES + dst[i]) * NCHUNK + sv / CHDIV;
        const int pos = atomicAdd(&cursor[b], 1);
        if (pos < CAP_SUB)
            epack[(size_t)b * CAP_SUB + pos] = (unsigned int)sv | (((unsigned int)f2bf(w[i])) << 16);
    }
}

// ---------------- fused: chunk-phased gather -> h (LDS) -> h @ W via MFMA ----------------
// 16-node dst tile, 512 threads (8 waves). Phase 1: each 32-lane half owns one
// node; per support, iterate 4 src-chunk sub-buckets in chunk order (all blocks
// sweep chunks identically -> chip-wide hot xb slice ~2.56-5 MB, L2-resident);
// each edge = ONE ushort8 (16 B/lane) load, ILP-4 via uint4 record loads.
// Phase 2: wave = 2 n-tiles x 24 k-steps (round-2-verified mapping).
__global__ void __launch_bounds__(512) fused_gather_gemm(
        const unsigned short* __restrict__ xb, const unsigned short* __restrict__ wt,
        const int* __restrict__ cursor, const unsigned int* __restrict__ epack,
        float* __restrict__ out) {
    __shared__ unsigned short h[TILE][HPAD];   // 24,832 B
    const int n0 = blockIdx.x * TILE;
    const int wid = threadIdx.x >> 6;
    const int lane = threadIdx.x & 63;
    const int half = lane >> 5;
    const int l32 = lane & 31;
    const int xoff = l32 * 8;                  // 16 B slice of the 512 B x-row

    // ---- phase 1: half -> one node; supports serial; chunks in order ----
    const int lr = wid * 2 + half;
    const int node = n0 + lr;
#pragma unroll
    for (int s = 0; s < N_SUPPORT; ++s) {
        const size_t brow = (size_t)(s * N_NODES + node) * NCHUNK;
        uint4 cn = *(const uint4*)(cursor + brow);   // 4 sub-bucket counts

        float a[8];
#pragma unroll
        for (int j = 0; j < 8; ++j) a[j] = 0.f;

#pragma unroll
        for (int p = 0; p < NCHUNK; ++p) {
            int cnt = (p == 0) ? cn.x : (p == 1) ? cn.y : (p == 2) ? cn.z : cn.w;
            if (cnt > CAP_SUB) cnt = CAP_SUB;
            const unsigned int* ep = epack + (brow + p) * CAP_SUB;

            int it = 0;
            for (; it + 3 < cnt; it += 4) {    // 4 independent x-row loads in flight
                const uint4 pk = *(const uint4*)(ep + it);
                ushort8 v0 = *(const ushort8*)(xb + (size_t)(pk.x & 0xFFFFu) * D_FEAT + xoff);
                ushort8 v1 = *(const ushort8*)(xb + (size_t)(pk.y & 0xFFFFu) * D_FEAT + xoff);
                ushort8 v2 = *(const ushort8*)(xb + (size_t)(pk.z & 0xFFFFu) * D_FEAT + xoff);
                ushort8 v3 = *(const ushort8*)(xb + (size_t)(pk.w & 0xFFFFu) * D_FEAT + xoff);
                const float w0 = __uint_as_float(pk.x & 0xFFFF0000u);
                const float w1 = __uint_as_float(pk.y & 0xFFFF0000u);
                const float w2 = __uint_as_float(pk.z & 0xFFFF0000u);
                const float w3 = __uint_as_float(pk.w & 0xFFFF0000u);
#pragma unroll
                for (int j = 0; j < 8; ++j) {
                    a[j] += w0 * bf2f(v0[j]) + w1 * bf2f(v1[j]);
                    a[j] += w2 * bf2f(v2[j]) + w3 * bf2f(v3[j]);
                }
            }
            for (; it < cnt; ++it) {           // <=3 cleanup iterations
                const unsigned int pe = ep[it];
                ushort8 v = *(const ushort8*)(xb + (size_t)(pe & 0xFFFFu) * D_FEAT + xoff);
                const float wv = __uint_as_float(pe & 0xFFFF0000u);
#pragma unroll
                for (int j = 0; j < 8; ++j) a[j] += wv * bf2f(v[j]);
            }
        }

        ushort8 o;
#pragma unroll
        for (int j = 0; j < 8; ++j) o[j] = f2bf(a[j]);
        *(ushort8*)&h[lr][s * D_FEAT + xoff] = o;
    }
    __syncthreads();

    // ---- phase 2: out_tile[16][256] = h @ W; wave -> 2 n-tiles ----
    const int cit = lane & 15;
    const int kgrp = (lane >> 4) * 8;

    f32x4 acc[2];
#pragma unroll
    for (int j = 0; j < 2; ++j) acc[j] = (f32x4){0.f, 0.f, 0.f, 0.f};

#pragma unroll
    for (int kk = 0; kk < KDIM / 32; ++kk) {   // 24 k-steps
        const int k0 = kk * 32;
        short8 av = *(const short8*)&h[cit][k0 + kgrp];
        const int s = k0 >> 8;
        const int kp = (k0 & 255) + kgrp;
        const short* bbase = (const short*)wt + (size_t)s * D_FEAT * OUT_DIM
                           + (size_t)cit * D_FEAT + kp;
#pragma unroll
        for (int j = 0; j < 2; ++j) {
            const int nt = wid * 2 + j;
            short8 bv = *(const short8*)(bbase + (size_t)nt * 16 * D_FEAT);
            acc[j] = __builtin_amdgcn_mfma_f32_16x16x32_bf16(av, bv, acc[j], 0, 0, 0);
        }
    }

    // C-write (round-2-verified mapping): row = rbase+r, col = nt*16 + cit
    const int rbase = (lane >> 4) * 4;
#pragma unroll
    for (int j = 0; j < 2; ++j) {
        const int col = (wid * 2 + j) * 16 + cit;
#pragma unroll
        for (int r = 0; r < 4; ++r) {
            out[(size_t)(n0 + rbase + r) * OUT_DIM + col] = acc[j][r];
        }
    }
}

extern "C" void kernel_launch(void* const* d_in, const int* in_sizes, int n_in,
                              void* d_out, int out_size, void* d_ws, size_t ws_size,
                              hipStream_t stream) {
    const float* x        = (const float*)d_in[0];
    const int*   edge_src = (const int*)d_in[1];
    const int*   edge_dst = (const int*)d_in[2];
    const float* edge_w   = (const float*)d_in[3];
    const float* W        = (const float*)d_in[4];
    float* out = (float*)d_out;

    char* ws = (char*)d_ws;
    unsigned short* xb     = (unsigned short*)(ws);              // 10,240,000 B
    unsigned short* wt     = (unsigned short*)(ws + 10240000);   //    393,216 B
    int*            cursor = (int*)(ws + 10633216);              //    960,000 B (60000*4 ints)
    unsigned int*   epack  = (unsigned int*)(ws + 11593216);     // 23,040,000 B (240000*24*4)
    // total: 34,633,216 B

    hipMemsetAsync(cursor, 0, 960000, stream);

    prep<<<NB_X + NB_W + NB_F, 256, 0, stream>>>(x, W, edge_src, edge_dst, edge_w,
                                                 xb, wt, cursor, epack);

    fused_gather_gemm<<<N_NODES / TILE, 512, 0, stream>>>(xb, wt, cursor, epack, out);
}

// Round 13
// 161.578 us; speedup vs baseline: 1.5096x; 1.2774x over previous
//
#include <hip/hip_runtime.h>

#define N_NODES 20000
#define D_FEAT 256
#define N_SUPPORT 3
#define N_EDGES 320000
#define OUT_DIM 256
#define TOTAL_E (N_SUPPORT * N_EDGES)
#define CAP 64                      // per-(s,dst) bucket; mean 16, P(>64) ~ 1e-9
#define KDIM (N_SUPPORT * D_FEAT)   // 768
#define HPAD (KDIM + 8)             // 776 shorts; rows 16B-aligned
#define TILE 16

typedef __attribute__((ext_vector_type(8))) short short8;
typedef __attribute__((ext_vector_type(8))) unsigned short ushort8;
typedef __attribute__((ext_vector_type(4))) float f32x4;

__device__ inline unsigned short f2bf(float f) {
    unsigned int u = __float_as_uint(f);
    u += 0x7fff + ((u >> 16) & 1);  // round-to-nearest-even
    return (unsigned short)(u >> 16);
}

// ---------------- prep1: quantize_x | convert_w (producers) ----------------
#define NB_X (N_NODES / 4)          // 5000 blocks, 4 waves/block, 1 row/wave
#define NB_W (N_SUPPORT * D_FEAT)   // 768
#define NB_F (TOTAL_E / 256)        // 3750

__global__ void __launch_bounds__(256) prep1(const float* __restrict__ x, const float* __restrict__ W,
        unsigned int* __restrict__ xq, float* __restrict__ scl, unsigned short* __restrict__ wt) {
    const int bid = blockIdx.x;
    const int tid = threadIdx.x;
    if (bid < NB_X) {
        // per-row int8 quantization: row = bid*4 + wid, lane owns 4 cols
        const int row = bid * 4 + (tid >> 6);
        const int lane = tid & 63;
        float4 v = ((const float4*)x)[row * 64 + lane];
        float m = fmaxf(fmaxf(fabsf(v.x), fabsf(v.y)), fmaxf(fabsf(v.z), fabsf(v.w)));
#pragma unroll
        for (int d = 1; d < 64; d <<= 1) m = fmaxf(m, __shfl_xor(m, d, 64));
        const float inv = (m > 0.f) ? 127.0f / m : 0.f;
        int q0 = (int)rintf(v.x * inv) + 128;
        int q1 = (int)rintf(v.y * inv) + 128;
        int q2 = (int)rintf(v.z * inv) + 128;
        int q3 = (int)rintf(v.w * inv) + 128;
        unsigned int pk = (unsigned int)q0 | ((unsigned int)q1 << 8)
                        | ((unsigned int)q2 << 16) | ((unsigned int)q3 << 24);
        xq[row * 64 + lane] = pk;
        if (lane == 0) scl[row] = m * (1.0f / 127.0f);
    } else {
        const int row = bid - NB_X;        // s*256 + k
        const int s = row >> 8, k = row & 255;
        wt[((size_t)s * OUT_DIM + tid) * D_FEAT + k] = f2bf(W[(size_t)row * OUT_DIM + tid]);
    }
}

// ---------------- prep2: fill_edges (consumer of scl, separate launch) ----------------
__global__ void __launch_bounds__(256) prep2(const int* __restrict__ src, const int* __restrict__ dst,
        const float* __restrict__ w, const float* __restrict__ scl,
        int* __restrict__ cursor, unsigned int* __restrict__ epack) {
    const int i = blockIdx.x * 256 + threadIdx.x;
    if (i >= TOTAL_E) return;
    const int s = i / N_EDGES;
    const int sv = src[i];
    const int b = s * N_NODES + dst[i];
    const int pos = atomicAdd(&cursor[b], 1);
    if (pos < CAP) {
        const float wq = w[i] * scl[sv];   // fold dequant scale into edge weight
        epack[(size_t)b * CAP + pos] = (unsigned int)sv | (((unsigned int)f2bf(wq)) << 16);
    }
}

// ---------------- fused: int8 gather -> h (LDS) -> h @ W via MFMA ----------------
// 16-node dst tile, 512 threads (8 waves). Phase 1: each 32-lane half owns one
// node; 3 supports serial; per edge ONE uint2 (8 B = 8 int8 cols) per lane,
// ILP-4 via uint4 record loads; bias folded out via sumw. Phase 2 unchanged.
__global__ void __launch_bounds__(512) fused_gather_gemm(
        const unsigned char* __restrict__ xq, const unsigned short* __restrict__ wt,
        const int* __restrict__ cursor, const unsigned int* __restrict__ epack,
        float* __restrict__ out) {
    __shared__ unsigned short h[TILE][HPAD];   // 24,832 B
    const int n0 = blockIdx.x * TILE;
    const int wid = threadIdx.x >> 6;
    const int lane = threadIdx.x & 63;
    const int half = lane >> 5;
    const int l32 = lane & 31;
    const int xoff = l32 * 8;                  // 8 cols x 1 B

    // ---- phase 1: half -> one node, 3 supports serial ----
    const int lr = wid * 2 + half;
    const int node = n0 + lr;
#pragma unroll
    for (int s = 0; s < N_SUPPORT; ++s) {
        const int b = s * N_NODES + node;
        int cnt = cursor[b]; if (cnt > CAP) cnt = CAP;
        const unsigned int* ep = epack + (size_t)b * CAP;

        float a[8];
#pragma unroll
        for (int j = 0; j < 8; ++j) a[j] = 0.f;
        float sw = 0.f;

        int it = 0;
        for (; it + 3 < cnt; it += 4) {        // 4 independent 8B table loads in flight
            const uint4 pk = *(const uint4*)(ep + it);
            const uint2 u0 = *(const uint2*)(xq + ((size_t)(pk.x & 0xFFFFu) << 8) + xoff);
            const uint2 u1 = *(const uint2*)(xq + ((size_t)(pk.y & 0xFFFFu) << 8) + xoff);
            const uint2 u2 = *(const uint2*)(xq + ((size_t)(pk.z & 0xFFFFu) << 8) + xoff);
            const uint2 u3 = *(const uint2*)(xq + ((size_t)(pk.w & 0xFFFFu) << 8) + xoff);
            const float w0 = __uint_as_float(pk.x & 0xFFFF0000u);
            const float w1 = __uint_as_float(pk.y & 0xFFFF0000u);
            const float w2 = __uint_as_float(pk.z & 0xFFFF0000u);
            const float w3 = __uint_as_float(pk.w & 0xFFFF0000u);
            sw += w0 + w1 + w2 + w3;
#pragma unroll
            for (int j = 0; j < 4; ++j) {
                const int sh = 8 * j;
                a[j]     += w0 * (float)((u0.x >> sh) & 0xffu) + w1 * (float)((u1.x >> sh) & 0xffu)
                          + w2 * (float)((u2.x >> sh) & 0xffu) + w3 * (float)((u3.x >> sh) & 0xffu);
                a[4 + j] += w0 * (float)((u0.y >> sh) & 0xffu) + w1 * (float)((u1.y >> sh) & 0xffu)
                          + w2 * (float)((u2.y >> sh) & 0xffu) + w3 * (float)((u3.y >> sh) & 0xffu);
            }
        }
        for (; it < cnt; ++it) {               // <=3 cleanup iterations
            const unsigned int pe = ep[it];
            const uint2 u = *(const uint2*)(xq + ((size_t)(pe & 0xFFFFu) << 8) + xoff);
            const float wv = __uint_as_float(pe & 0xFFFF0000u);
            sw += wv;
#pragma unroll
            for (int j = 0; j < 4; ++j) {
                const int sh = 8 * j;
                a[j]     += wv * (float)((u.x >> sh) & 0xffu);
                a[4 + j] += wv * (float)((u.y >> sh) & 0xffu);
            }
        }

        ushort8 o;
        const float bias = 128.f * sw;
#pragma unroll
        for (int j = 0; j < 8; ++j) o[j] = f2bf(a[j] - bias);
        *(ushort8*)&h[lr][s * D_FEAT + xoff] = o;
    }
    __syncthreads();

    // ---- phase 2: out_tile[16][256] = h @ W; wave -> 2 n-tiles ----
    const int cit = lane & 15;
    const int kgrp = (lane >> 4) * 8;

    f32x4 acc[2];
#pragma unroll
    for (int j = 0; j < 2; ++j) acc[j] = (f32x4){0.f, 0.f, 0.f, 0.f};

#pragma unroll
    for (int kk = 0; kk < KDIM / 32; ++kk) {   // 24 k-steps
        const int k0 = kk * 32;
        short8 av = *(const short8*)&h[cit][k0 + kgrp];
        const int s = k0 >> 8;
        const int kp = (k0 & 255) + kgrp;
        const short* bbase = (const short*)wt + (size_t)s * D_FEAT * OUT_DIM
                           + (size_t)cit * D_FEAT + kp;
#pragma unroll
        for (int j = 0; j < 2; ++j) {
            const int nt = wid * 2 + j;
            short8 bv = *(const short8*)(bbase + (size_t)nt * 16 * D_FEAT);
            acc[j] = __builtin_amdgcn_mfma_f32_16x16x32_bf16(av, bv, acc[j], 0, 0, 0);
        }
    }

    // C-write (round-2-verified mapping): row = rbase+r, col = nt*16 + cit
    const int rbase = (lane >> 4) * 4;
#pragma unroll
    for (int j = 0; j < 2; ++j) {
        const int col = (wid * 2 + j) * 16 + cit;
#pragma unroll
        for (int r = 0; r < 4; ++r) {
            out[(size_t)(n0 + rbase + r) * OUT_DIM + col] = acc[j][r];
        }
    }
}

extern "C" void kernel_launch(void* const* d_in, const int* in_sizes, int n_in,
                              void* d_out, int out_size, void* d_ws, size_t ws_size,
                              hipStream_t stream) {
    const float* x        = (const float*)d_in[0];
    const int*   edge_src = (const int*)d_in[1];
    const int*   edge_dst = (const int*)d_in[2];
    const float* edge_w   = (const float*)d_in[3];
    const float* W        = (const float*)d_in[4];
    float* out = (float*)d_out;

    char* ws = (char*)d_ws;
    unsigned int*   xq     = (unsigned int*)(ws);                // 5,120,000 B (int8 table)
    float*          scl    = (float*)(ws + 5120000);             //    80,000 B
    unsigned short* wt     = (unsigned short*)(ws + 5200000);    //   393,216 B
    int*            cursor = (int*)(ws + 5593216);               //   240,000 B
    unsigned int*   epack  = (unsigned int*)(ws + 5833216);      // 15,360,000 B
    // total: 21,193,216 B

    hipMemsetAsync(cursor, 0, 240000, stream);

    prep1<<<NB_X + NB_W, 256, 0, stream>>>(x, W, xq, scl, wt);
    prep2<<<NB_F, 256, 0, stream>>>(edge_src, edge_dst, edge_w, scl, cursor, epack);

    fused_gather_gemm<<<N_NODES / TILE, 512, 0, stream>>>((const unsigned char*)xq, wt,
                                                          cursor, epack, out);
}